// Round 9
// baseline (447.172 us; speedup 1.0000x reference)
//
#include <hip/hip_runtime.h>
#include <math.h>
#include <float.h>

// Problem constants (from reference)
#define NN 20000      // nodes
#define EE 640000     // edges
#define HH 2          // heads
#define DD 64         // dim
#define LL 4          // layers
#define HD 128        // H*D
#define NB 8          // src-range buckets per node
#define BSZ 2500      // bucket width in src rows

// ---------------- DPP helper (intra-16-lane sum, pure VALU) ----------------

__device__ __forceinline__ float row16_sum(float x) {
    int t;
    t = __builtin_amdgcn_update_dpp(0, __float_as_int(x), 0xB1, 0xF, 0xF, true);  // quad_perm [1,0,3,2]
    x += __int_as_float(t);
    t = __builtin_amdgcn_update_dpp(0, __float_as_int(x), 0x4E, 0xF, 0xF, true);  // quad_perm [2,3,0,1]
    x += __int_as_float(t);
    t = __builtin_amdgcn_update_dpp(0, __float_as_int(x), 0x124, 0xF, 0xF, true); // row_ror:4
    x += __int_as_float(t);
    t = __builtin_amdgcn_update_dpp(0, __float_as_int(x), 0x128, 0xF, 0xF, true); // row_ror:8
    x += __int_as_float(t);
    return x;
}

// ---------------- CSR build (bucketed) ----------------

__global__ void hist_kernel(const int* __restrict__ src, const int* __restrict__ dst,
                            int* __restrict__ bdeg) {
    int e = blockIdx.x * 256 + threadIdx.x;
    if (e < EE) {
        int b = (unsigned)src[e] / BSZ;
        atomicAdd(&bdeg[dst[e] * NB + b], 1);
    }
}

__global__ void bucket_sum_kernel(const int* __restrict__ bdeg, int* __restrict__ deg) {
    int n = blockIdx.x * 256 + threadIdx.x;
    if (n >= NN) return;
    int s = 0;
#pragma unroll
    for (int b = 0; b < NB; ++b) s += bdeg[n * NB + b];
    deg[n] = s;
}

// single-block exclusive scan, 1024 threads, wave-shuffle based
__global__ void scan_kernel(const int* __restrict__ deg, int* __restrict__ offsets, int n) {
    __shared__ int wsum[16];
    __shared__ int carry;
    int tid = threadIdx.x, wid = tid >> 6, lane = tid & 63;
    if (tid == 0) carry = 0;
    __syncthreads();
    for (int base = 0; base < n; base += 1024) {
        int i = base + tid;
        int v = (i < n) ? deg[i] : 0;
        int x = v;
#pragma unroll
        for (int off = 1; off < 64; off <<= 1) {
            int t = __shfl_up(x, off);
            if (lane >= off) x += t;
        }
        if (lane == 63) wsum[wid] = x;
        __syncthreads();
        if (wid == 0) {
            int wv = (lane < 16) ? wsum[lane] : 0;
#pragma unroll
            for (int off = 1; off < 16; off <<= 1) {
                int t = __shfl_up(wv, off);
                if (lane >= off) wv += t;
            }
            if (lane < 16) wsum[lane] = wv;   // inclusive wave sums
        }
        __syncthreads();
        int prefix = carry + (wid > 0 ? wsum[wid - 1] : 0);
        if (i < n) offsets[i] = prefix + x - v;   // exclusive
        __syncthreads();
        if (tid == 0) carry += wsum[15];
        __syncthreads();
    }
    if (threadIdx.x == 0) offsets[n] = carry;
}

__global__ void bucket_prefix_kernel(const int* __restrict__ bdeg, const int* __restrict__ offsets,
                                     int* __restrict__ cursor) {
    int n = blockIdx.x * 256 + threadIdx.x;
    if (n >= NN) return;
    int base = offsets[n];
#pragma unroll
    for (int b = 0; b < NB; ++b) {
        cursor[n * NB + b] = base;
        base += bdeg[n * NB + b];
    }
}

__global__ void scatter_kernel(const int* __restrict__ src, const int* __restrict__ dst,
                               int* __restrict__ cursor, int* __restrict__ csr_src) {
    int e = blockIdx.x * 256 + threadIdx.x;
    if (e >= EE) return;
    int s = src[e];
    int b = (unsigned)s / BSZ;
    int pos = atomicAdd(&cursor[dst[e] * NB + b], 1);
    csr_src[pos] = s;
}

// ---------------- per-layer kernels ----------------

// xl = x@Wl + bl ; xr = x@Wr + br  ([N,64] x [64,128])
// 8 rows/block, 128 threads. W staged through LDS in 16-k chunks (coalesced
// float4, high-MLP) so the k-loop has NO global latency -> FMA-issue-bound.
__global__ void __launch_bounds__(128) gemm_lr(
        const float* __restrict__ x,
        const float* __restrict__ Wl, const float* __restrict__ bl,
        const float* __restrict__ Wr, const float* __restrict__ br,
        float* __restrict__ xl, float* __restrict__ xr) {
    __shared__ float xs[8][DD];
    __shared__ float wls[16][HD], wrs[16][HD];
    int tid = threadIdx.x;
    int row0 = blockIdx.x * 8;
    ((float4*)xs)[tid] = ((const float4*)(x + (size_t)row0 * DD))[tid];
    int j = tid;
    float accl[8], accr[8];
    float blv = bl[j], brv = br[j];
#pragma unroll
    for (int r = 0; r < 8; ++r) { accl[r] = blv; accr[r] = brv; }

    for (int kc = 0; kc < DD; kc += 16) {
        __syncthreads();   // covers xs on first pass, prev-chunk reads after
        const float4* gl = (const float4*)(Wl + (size_t)kc * HD);
        const float4* gr = (const float4*)(Wr + (size_t)kc * HD);
#pragma unroll
        for (int q = 0; q < 4; ++q) {
            ((float4*)wls)[tid + 128 * q] = gl[tid + 128 * q];
            ((float4*)wrs)[tid + 128 * q] = gr[tid + 128 * q];
        }
        __syncthreads();
#pragma unroll
        for (int kk = 0; kk < 16; ++kk) {
            float wl = wls[kk][j];
            float wr = wrs[kk][j];
#pragma unroll
            for (int r = 0; r < 8; ++r) {
                float xv = xs[r][kc + kk];
                accl[r] = fmaf(xv, wl, accl[r]);
                accr[r] = fmaf(xv, wr, accr[r]);
            }
        }
    }
#pragma unroll
    for (int r = 0; r < 8; ++r) {
        xl[(row0 + r) * HD + j] = accl[r];
        xr[(row0 + r) * HD + j] = accr[r];
    }
}

// Fused GATv2 edge phase: one wave per node, 4 edges per iteration.
// EXACT round-6 loop structure (online-max softmax, fmaxf/fminf leaky, depth-1
// prefetch, group-private state, rescaled butterfly merge) — round 7's "cheaper"
// no-max variant regressed 45->56 us: the max/exp chain was overlapping gather
// latency. FINAL variant fuses out = leaky(o @ Wo + bo, 0.01) via an LDS bounce.
template <bool FINAL>
__global__ void fused_aggregate(const float* __restrict__ xl, const float* __restrict__ xr,
                                const float* __restrict__ att, const int* __restrict__ offsets,
                                const int* __restrict__ csr_src, const float* __restrict__ bias,
                                const float* __restrict__ Wo, const float* __restrict__ bo,
                                float* __restrict__ xout) {
    int lane = threadIdx.x & 63;
    int w = threadIdx.x >> 6;
    int node = blockIdx.x * 4 + w;
    int g = lane >> 4;
    int fo = (lane & 15) * 4;

    int start = offsets[node];
    int deg = offsets[node + 1] - start;

    unsigned nrow = (unsigned)node << 7;
    const float4 xra = *(const float4*)&xr[nrow + fo];
    const float4 xrb = *(const float4*)&xr[nrow + 64 + fo];
    const float4 ata = *(const float4*)&att[fo];
    const float4 atb = *(const float4*)&att[64 + fo];

    float ma = -FLT_MAX, mb = -FLT_MAX;   // per-group running max, per head
    float sa = 0.f, sb = 0.f;             // per-group denom
    float4 aa = {0.f, 0.f, 0.f, 0.f};     // per-group weighted message, head 0
    float4 ab = {0.f, 0.f, 0.f, 0.f};     // head 1

    if (deg > 0) {
        int dend = start + deg - 1;       // clamp target for branchless prefetch
        int niter = (deg + 3) >> 2;

        int s_cur = csr_src[min(start + g, dend)];
        int s_nxt = csr_src[min(start + 4 + g, dend)];
        unsigned rc = (unsigned)s_cur << 7;
        float4 xa = *(const float4*)&xl[rc + fo];
        float4 xb = *(const float4*)&xl[rc + 64 + fo];

        for (int i = 0; i < niter; ++i) {
            // prefetch rows for iter i+1 and index for iter i+2 (clamped, branchless)
            unsigned rn = (unsigned)s_nxt << 7;
            float4 na = *(const float4*)&xl[rn + fo];
            float4 nb = *(const float4*)&xl[rn + 64 + fo];
            int s_n2 = csr_src[min(start + 4 * i + 8 + g, dend)];

            // logit partials: att . leaky_relu(xl + xr, 0.2), both heads
            float4 va, vb;
            va.x = xa.x + xra.x; va.y = xa.y + xra.y; va.z = xa.z + xra.z; va.w = xa.w + xra.w;
            vb.x = xb.x + xrb.x; vb.y = xb.y + xrb.y; vb.z = xb.z + xrb.z; vb.w = xb.w + xrb.w;
            va.x = fmaxf(va.x, 0.f) + 0.2f * fminf(va.x, 0.f);
            va.y = fmaxf(va.y, 0.f) + 0.2f * fminf(va.y, 0.f);
            va.z = fmaxf(va.z, 0.f) + 0.2f * fminf(va.z, 0.f);
            va.w = fmaxf(va.w, 0.f) + 0.2f * fminf(va.w, 0.f);
            vb.x = fmaxf(vb.x, 0.f) + 0.2f * fminf(vb.x, 0.f);
            vb.y = fmaxf(vb.y, 0.f) + 0.2f * fminf(vb.y, 0.f);
            vb.z = fmaxf(vb.z, 0.f) + 0.2f * fminf(vb.z, 0.f);
            vb.w = fmaxf(vb.w, 0.f) + 0.2f * fminf(vb.w, 0.f);
            float ta = fmaf(va.x, ata.x, fmaf(va.y, ata.y, fmaf(va.z, ata.z, va.w * ata.w)));
            float tb = fmaf(vb.x, atb.x, fmaf(vb.y, atb.y, fmaf(vb.z, atb.z, vb.w * atb.w)));
            ta = row16_sum(ta);           // pure-VALU intra-group reduction
            tb = row16_sum(tb);

            bool valid = (4 * i + g) < deg;
            float lga = valid ? ta : -FLT_MAX;
            float lgb = valid ? tb : -FLT_MAX;

            // group-local online softmax update, head 0
            float mna = fmaxf(ma, lga);
            float ca = __expf(ma - mna);
            float wa = __expf(lga - mna);
            sa = fmaf(sa, ca, wa);
            aa.x = fmaf(aa.x, ca, wa * xa.x);
            aa.y = fmaf(aa.y, ca, wa * xa.y);
            aa.z = fmaf(aa.z, ca, wa * xa.z);
            aa.w = fmaf(aa.w, ca, wa * xa.w);
            ma = mna;
            // head 1
            float mnb = fmaxf(mb, lgb);
            float cb = __expf(mb - mnb);
            float wb = __expf(lgb - mnb);
            sb = fmaf(sb, cb, wb);
            ab.x = fmaf(ab.x, cb, wb * xb.x);
            ab.y = fmaf(ab.y, cb, wb * xb.y);
            ab.z = fmaf(ab.z, cb, wb * xb.z);
            ab.w = fmaf(ab.w, cb, wb * xb.w);
            mb = mnb;

            xa = na; xb = nb;
            s_nxt = s_n2;
        }
    }

    // merge the 4 group states: butterfly with exp rescale
#pragma unroll
    for (int off = 16; off <= 32; off <<= 1) {
        float mo = __shfl_xor(ma, off);
        float so = __shfl_xor(sa, off);
        float4 ao;
        ao.x = __shfl_xor(aa.x, off); ao.y = __shfl_xor(aa.y, off);
        ao.z = __shfl_xor(aa.z, off); ao.w = __shfl_xor(aa.w, off);
        float mn = fmaxf(ma, mo);
        float c0 = __expf(ma - mn), c1 = __expf(mo - mn);
        sa = fmaf(sa, c0, so * c1);
        aa.x = fmaf(aa.x, c0, ao.x * c1);
        aa.y = fmaf(aa.y, c0, ao.y * c1);
        aa.z = fmaf(aa.z, c0, ao.z * c1);
        aa.w = fmaf(aa.w, c0, ao.w * c1);
        ma = mn;

        mo = __shfl_xor(mb, off);
        so = __shfl_xor(sb, off);
        ao.x = __shfl_xor(ab.x, off); ao.y = __shfl_xor(ab.y, off);
        ao.z = __shfl_xor(ab.z, off); ao.w = __shfl_xor(ab.w, off);
        mn = fmaxf(mb, mo);
        c0 = __expf(mb - mn); c1 = __expf(mo - mn);
        sb = fmaf(sb, c0, so * c1);
        ab.x = fmaf(ab.x, c0, ao.x * c1);
        ab.y = fmaf(ab.y, c0, ao.y * c1);
        ab.z = fmaf(ab.z, c0, ao.z * c1);
        ab.w = fmaf(ab.w, c0, ao.w * c1);
        mb = mn;
    }

    float inva = 1.0f / (sa + 1e-16f);    // deg==0 -> acc=0 -> r=0
    float invb = 1.0f / (sb + 1e-16f);

    if (!FINAL) {
        if (lane < 16) {
            const float4 bv = *(const float4*)&bias[fo];
            float4 o;
            o.x = fmaf(0.5f, fmaf(aa.x, inva, ab.x * invb), bv.x);
            o.y = fmaf(0.5f, fmaf(aa.y, inva, ab.y * invb), bv.y);
            o.z = fmaf(0.5f, fmaf(aa.z, inva, ab.z * invb), bv.z);
            o.w = fmaf(0.5f, fmaf(aa.w, inva, ab.w * invb), bv.w);
            o.x = o.x > 0.f ? o.x : 0.01f * o.x;
            o.y = o.y > 0.f ? o.y : 0.01f * o.y;
            o.z = o.z > 0.f ? o.z : 0.01f * o.z;
            o.w = o.w > 0.f ? o.w : 0.01f * o.w;
            *(float4*)&xout[(size_t)node * DD + fo] = o;
        }
    } else {
        // epilogue GEMM: out = leaky(o @ Wo + bo, 0.01), o bounced through LDS
        __shared__ float sh_o[4][DD];
        if (lane < 16) {
            const float4 bv = *(const float4*)&bias[fo];
            float4 o;
            o.x = fmaf(0.5f, fmaf(aa.x, inva, ab.x * invb), bv.x);
            o.y = fmaf(0.5f, fmaf(aa.y, inva, ab.y * invb), bv.y);
            o.z = fmaf(0.5f, fmaf(aa.z, inva, ab.z * invb), bv.z);
            o.w = fmaf(0.5f, fmaf(aa.w, inva, ab.w * invb), bv.w);
            o.x = o.x > 0.f ? o.x : 0.01f * o.x;
            o.y = o.y > 0.f ? o.y : 0.01f * o.y;
            o.z = o.z > 0.f ? o.z : 0.01f * o.z;
            o.w = o.w > 0.f ? o.w : 0.01f * o.w;
            *(float4*)&sh_o[w][fo] = o;
        }
        __syncthreads();
        int j = lane;                      // output column
        float acc = bo[j];
#pragma unroll 4
        for (int k = 0; k < DD; ++k) {
            acc = fmaf(sh_o[w][k], Wo[k * DD + j], acc);
        }
        acc = acc > 0.f ? acc : 0.01f * acc;
        xout[(size_t)node * DD + j] = acc;
    }
}

extern "C" void kernel_launch(void* const* d_in, const int* in_sizes, int n_in,
                              void* d_out, int out_size, void* d_ws, size_t ws_size,
                              hipStream_t stream) {
    const int* edge_index = (const int*)d_in[0];
    const int* src = edge_index;
    const int* dst = edge_index + EE;
    // d_in[1] = edge_weight, unused
    const float* pert = (const float*)d_in[2];
    const float* Wl = (const float*)d_in[3];
    const float* bl = (const float*)d_in[4];
    const float* Wr = (const float*)d_in[5];
    const float* br = (const float*)d_in[6];
    const float* att = (const float*)d_in[7];
    const float* bias = (const float*)d_in[8];
    const float* Wo = (const float*)d_in[9];
    const float* bo = (const float*)d_in[10];
    float* out = (float*)d_out;

    // workspace carve-up
    char* w = (char*)d_ws;
    float* xl = (float*)w;            w += (size_t)NN * HD * 4;
    float* xr = (float*)w;            w += (size_t)NN * HD * 4;
    float* xb0 = (float*)w;           w += (size_t)NN * DD * 4;
    float* xb1 = (float*)w;           w += (size_t)NN * DD * 4;
    int* bdeg = (int*)w;              w += (size_t)NN * NB * 4;
    int* deg = (int*)w;               w += (size_t)NN * 4;
    int* offsets = (int*)w;           w += (size_t)(NN + 1) * 4 + 4; // keep alignment
    int* cursor = (int*)w;            w += (size_t)NN * NB * 4;
    int* csr_src = (int*)w;           w += (size_t)EE * 4;

    // Bucketed CSR build (dst is layer-invariant; built once per launch)
    hipMemsetAsync(bdeg, 0, (size_t)NN * NB * 4, stream);
    hist_kernel<<<(EE + 255) / 256, 256, 0, stream>>>(src, dst, bdeg);
    bucket_sum_kernel<<<(NN + 255) / 256, 256, 0, stream>>>(bdeg, deg);
    scan_kernel<<<1, 1024, 0, stream>>>(deg, offsets, NN);
    bucket_prefix_kernel<<<(NN + 255) / 256, 256, 0, stream>>>(bdeg, offsets, cursor);
    scatter_kernel<<<(EE + 255) / 256, 256, 0, stream>>>(src, dst, cursor, csr_src);

    const float* xin = pert;
    float* bufs[2] = {xb0, xb1};
    for (int l = 0; l < LL; ++l) {
        gemm_lr<<<NN / 8, 128, 0, stream>>>(xin, Wl + (size_t)l * DD * HD, bl + (size_t)l * HD,
                                            Wr + (size_t)l * DD * HD, br + (size_t)l * HD, xl, xr);
        if (l < LL - 1) {
            fused_aggregate<false><<<NN / 4, 256, 0, stream>>>(
                xl, xr, att + (size_t)l * HD, offsets, csr_src,
                bias + (size_t)l * DD, nullptr, nullptr, bufs[l & 1]);
            xin = bufs[l & 1];
        } else {
            fused_aggregate<true><<<NN / 4, 256, 0, stream>>>(
                xl, xr, att + (size_t)l * HD, offsets, csr_src,
                bias + (size_t)l * DD, Wo, bo, out);
        }
    }
}

// Round 10
// 393.645 us; speedup vs baseline: 1.1360x; 1.1360x over previous
//
#include <hip/hip_runtime.h>
#include <math.h>
#include <float.h>

// Problem constants (from reference)
#define NN 20000      // nodes
#define EE 640000     // edges
#define HH 2          // heads
#define DD 64         // dim
#define LL 4          // layers
#define HD 128        // H*D
#define NB 8          // src-range buckets per node
#define BSZ 2500      // bucket width in src rows
#define GR 32         // rows per gemm block

// ---------------- DPP helper (intra-16-lane sum, pure VALU) ----------------

__device__ __forceinline__ float row16_sum(float x) {
    int t;
    t = __builtin_amdgcn_update_dpp(0, __float_as_int(x), 0xB1, 0xF, 0xF, true);  // quad_perm [1,0,3,2]
    x += __int_as_float(t);
    t = __builtin_amdgcn_update_dpp(0, __float_as_int(x), 0x4E, 0xF, 0xF, true);  // quad_perm [2,3,0,1]
    x += __int_as_float(t);
    t = __builtin_amdgcn_update_dpp(0, __float_as_int(x), 0x124, 0xF, 0xF, true); // row_ror:4
    x += __int_as_float(t);
    t = __builtin_amdgcn_update_dpp(0, __float_as_int(x), 0x128, 0xF, 0xF, true); // row_ror:8
    x += __int_as_float(t);
    return x;
}

// ---------------- CSR build (bucketed) ----------------

__global__ void hist_kernel(const int* __restrict__ src, const int* __restrict__ dst,
                            int* __restrict__ bdeg) {
    int e = blockIdx.x * 256 + threadIdx.x;
    if (e < EE) {
        int b = (unsigned)src[e] / BSZ;
        atomicAdd(&bdeg[dst[e] * NB + b], 1);
    }
}

__global__ void bucket_sum_kernel(const int* __restrict__ bdeg, int* __restrict__ deg) {
    int n = blockIdx.x * 256 + threadIdx.x;
    if (n >= NN) return;
    int s = 0;
#pragma unroll
    for (int b = 0; b < NB; ++b) s += bdeg[n * NB + b];
    deg[n] = s;
}

// single-block exclusive scan, 1024 threads, wave-shuffle based
__global__ void scan_kernel(const int* __restrict__ deg, int* __restrict__ offsets, int n) {
    __shared__ int wsum[16];
    __shared__ int carry;
    int tid = threadIdx.x, wid = tid >> 6, lane = tid & 63;
    if (tid == 0) carry = 0;
    __syncthreads();
    for (int base = 0; base < n; base += 1024) {
        int i = base + tid;
        int v = (i < n) ? deg[i] : 0;
        int x = v;
#pragma unroll
        for (int off = 1; off < 64; off <<= 1) {
            int t = __shfl_up(x, off);
            if (lane >= off) x += t;
        }
        if (lane == 63) wsum[wid] = x;
        __syncthreads();
        if (wid == 0) {
            int wv = (lane < 16) ? wsum[lane] : 0;
#pragma unroll
            for (int off = 1; off < 16; off <<= 1) {
                int t = __shfl_up(wv, off);
                if (lane >= off) wv += t;
            }
            if (lane < 16) wsum[lane] = wv;   // inclusive wave sums
        }
        __syncthreads();
        int prefix = carry + (wid > 0 ? wsum[wid - 1] : 0);
        if (i < n) offsets[i] = prefix + x - v;   // exclusive
        __syncthreads();
        if (tid == 0) carry += wsum[15];
        __syncthreads();
    }
    if (threadIdx.x == 0) offsets[n] = carry;
}

__global__ void bucket_prefix_kernel(const int* __restrict__ bdeg, const int* __restrict__ offsets,
                                     int* __restrict__ cursor) {
    int n = blockIdx.x * 256 + threadIdx.x;
    if (n >= NN) return;
    int base = offsets[n];
#pragma unroll
    for (int b = 0; b < NB; ++b) {
        cursor[n * NB + b] = base;
        base += bdeg[n * NB + b];
    }
}

__global__ void scatter_kernel(const int* __restrict__ src, const int* __restrict__ dst,
                               int* __restrict__ cursor, int* __restrict__ csr_src) {
    int e = blockIdx.x * 256 + threadIdx.x;
    if (e >= EE) return;
    int s = src[e];
    int b = (unsigned)s / BSZ;
    int pos = atomicAdd(&cursor[dst[e] * NB + b], 1);
    csr_src[pos] = s;
}

// ---------------- per-layer kernels ----------------

// xl = x@Wl + bl ; xr = x@Wr + br  ([N,64] x [64,128] twice = one [N,64]x[64,256]).
// 2D register-tile GEMM: block = 32 rows x 256 cols, 256 threads, 8x4 micro-tile.
// Per 16-k chunk x (transposed) and W are staged in LDS; inner loop reads
// 1 b128 W + 2 b128 broadcast x per kk and issues 32 FMAs -> VALU-bound.
__global__ void __launch_bounds__(256) gemm_lr(
        const float* __restrict__ x,
        const float* __restrict__ Wl, const float* __restrict__ bl,
        const float* __restrict__ Wr, const float* __restrict__ br,
        float* __restrict__ xl, float* __restrict__ xr) {
    __shared__ float xs[16][GR];      // [kk][row], transposed
    __shared__ float ws[16][2 * HD];  // [kk][col], cols = [Wl row | Wr row]
    int tid = threadIdx.x;
    int row0 = blockIdx.x * GR;
    int tc = tid & 63;                 // col group: cols tc*4 .. tc*4+3 of 256
    int tr = tid >> 6;                 // row group: rows tr*8 .. tr*8+7 of 32
    int c0 = tc * 4;

    float4 bv;
    {
        const float* bsrc = (c0 < HD) ? (bl + c0) : (br + (c0 - HD));
        bv = *(const float4*)bsrc;
    }
    float acc[8][4];
#pragma unroll
    for (int r = 0; r < 8; ++r) {
        acc[r][0] = bv.x; acc[r][1] = bv.y; acc[r][2] = bv.z; acc[r][3] = bv.w;
    }

    // staging indices (constant across chunks)
    int sr = tid >> 3;            // 0..31 row for x staging
    int skk = (tid & 7) * 2;      // 0,2,..,14 k-pair for x staging

    for (int kc = 0; kc < DD; kc += 16) {
        __syncthreads();
        // stage x chunk: 32 rows x 16 k (transposed store)
        {
            float2 v = *(const float2*)&x[(size_t)(row0 + sr) * DD + kc + skk];
            xs[skk][sr] = v.x;
            xs[skk + 1][sr] = v.y;
        }
        // stage W chunk: 16 k x 256 cols, coalesced float4
#pragma unroll
        for (int q = 0; q < 4; ++q) {
            int idx = tid + 256 * q;          // 0..1023 float4 slots
            int kk = idx >> 6;                // 0..15
            int cc = (idx & 63) * 4;          // 0..252
            const float* srcp = (cc < HD) ? (Wl + (size_t)(kc + kk) * HD + cc)
                                          : (Wr + (size_t)(kc + kk) * HD + (cc - HD));
            *(float4*)&ws[kk][cc] = *(const float4*)srcp;
        }
        __syncthreads();
#pragma unroll
        for (int kk = 0; kk < 16; ++kk) {
            float4 wv = *(const float4*)&ws[kk][c0];
            float xv[8];
            *(float4*)&xv[0] = *(const float4*)&xs[kk][tr * 8];
            *(float4*)&xv[4] = *(const float4*)&xs[kk][tr * 8 + 4];
#pragma unroll
            for (int r = 0; r < 8; ++r) {
                acc[r][0] = fmaf(xv[r], wv.x, acc[r][0]);
                acc[r][1] = fmaf(xv[r], wv.y, acc[r][1]);
                acc[r][2] = fmaf(xv[r], wv.z, acc[r][2]);
                acc[r][3] = fmaf(xv[r], wv.w, acc[r][3]);
            }
        }
    }

    float* ybase = (c0 < HD) ? xl : xr;
    int cw = (c0 < HD) ? c0 : (c0 - HD);
#pragma unroll
    for (int r = 0; r < 8; ++r) {
        int row = row0 + tr * 8 + r;
        float4 o;
        o.x = acc[r][0]; o.y = acc[r][1]; o.z = acc[r][2]; o.w = acc[r][3];
        *(float4*)&ybase[(size_t)row * HD + cw] = o;
    }
}

// Fused GATv2 edge phase: one wave per node, 4 edges per iteration.
// Round-6 loop structure (online-max softmax, depth-1 prefetch, group-private
// state, rescaled butterfly merge) — round 7's no-max variant regressed 45->56 us.
// FINAL variant fuses out = leaky(o @ Wo + bo, 0.01) via an LDS bounce.
template <bool FINAL>
__global__ void fused_aggregate(const float* __restrict__ xl, const float* __restrict__ xr,
                                const float* __restrict__ att, const int* __restrict__ offsets,
                                const int* __restrict__ csr_src, const float* __restrict__ bias,
                                const float* __restrict__ Wo, const float* __restrict__ bo,
                                float* __restrict__ xout) {
    int lane = threadIdx.x & 63;
    int w = threadIdx.x >> 6;
    int node = blockIdx.x * 4 + w;
    int g = lane >> 4;
    int fo = (lane & 15) * 4;

    int start = offsets[node];
    int deg = offsets[node + 1] - start;

    unsigned nrow = (unsigned)node << 7;
    const float4 xra = *(const float4*)&xr[nrow + fo];
    const float4 xrb = *(const float4*)&xr[nrow + 64 + fo];
    const float4 ata = *(const float4*)&att[fo];
    const float4 atb = *(const float4*)&att[64 + fo];

    float ma = -FLT_MAX, mb = -FLT_MAX;   // per-group running max, per head
    float sa = 0.f, sb = 0.f;             // per-group denom
    float4 aa = {0.f, 0.f, 0.f, 0.f};     // per-group weighted message, head 0
    float4 ab = {0.f, 0.f, 0.f, 0.f};     // head 1

    if (deg > 0) {
        int dend = start + deg - 1;       // clamp target for branchless prefetch
        int niter = (deg + 3) >> 2;

        int s_cur = csr_src[min(start + g, dend)];
        int s_nxt = csr_src[min(start + 4 + g, dend)];
        unsigned rc = (unsigned)s_cur << 7;
        float4 xa = *(const float4*)&xl[rc + fo];
        float4 xb = *(const float4*)&xl[rc + 64 + fo];

        for (int i = 0; i < niter; ++i) {
            // prefetch rows for iter i+1 and index for iter i+2 (clamped, branchless)
            unsigned rn = (unsigned)s_nxt << 7;
            float4 na = *(const float4*)&xl[rn + fo];
            float4 nb = *(const float4*)&xl[rn + 64 + fo];
            int s_n2 = csr_src[min(start + 4 * i + 8 + g, dend)];

            // logit partials: att . leaky_relu(xl + xr, 0.2), both heads
            float4 va, vb;
            va.x = xa.x + xra.x; va.y = xa.y + xra.y; va.z = xa.z + xra.z; va.w = xa.w + xra.w;
            vb.x = xb.x + xrb.x; vb.y = xb.y + xrb.y; vb.z = xb.z + xrb.z; vb.w = xb.w + xrb.w;
            va.x = fmaxf(va.x, 0.f) + 0.2f * fminf(va.x, 0.f);
            va.y = fmaxf(va.y, 0.f) + 0.2f * fminf(va.y, 0.f);
            va.z = fmaxf(va.z, 0.f) + 0.2f * fminf(va.z, 0.f);
            va.w = fmaxf(va.w, 0.f) + 0.2f * fminf(va.w, 0.f);
            vb.x = fmaxf(vb.x, 0.f) + 0.2f * fminf(vb.x, 0.f);
            vb.y = fmaxf(vb.y, 0.f) + 0.2f * fminf(vb.y, 0.f);
            vb.z = fmaxf(vb.z, 0.f) + 0.2f * fminf(vb.z, 0.f);
            vb.w = fmaxf(vb.w, 0.f) + 0.2f * fminf(vb.w, 0.f);
            float ta = fmaf(va.x, ata.x, fmaf(va.y, ata.y, fmaf(va.z, ata.z, va.w * ata.w)));
            float tb = fmaf(vb.x, atb.x, fmaf(vb.y, atb.y, fmaf(vb.z, atb.z, vb.w * atb.w)));
            ta = row16_sum(ta);           // pure-VALU intra-group reduction
            tb = row16_sum(tb);

            bool valid = (4 * i + g) < deg;
            float lga = valid ? ta : -FLT_MAX;
            float lgb = valid ? tb : -FLT_MAX;

            // group-local online softmax update, head 0
            float mna = fmaxf(ma, lga);
            float ca = __expf(ma - mna);
            float wa = __expf(lga - mna);
            sa = fmaf(sa, ca, wa);
            aa.x = fmaf(aa.x, ca, wa * xa.x);
            aa.y = fmaf(aa.y, ca, wa * xa.y);
            aa.z = fmaf(aa.z, ca, wa * xa.z);
            aa.w = fmaf(aa.w, ca, wa * xa.w);
            ma = mna;
            // head 1
            float mnb = fmaxf(mb, lgb);
            float cb = __expf(mb - mnb);
            float wb = __expf(lgb - mnb);
            sb = fmaf(sb, cb, wb);
            ab.x = fmaf(ab.x, cb, wb * xb.x);
            ab.y = fmaf(ab.y, cb, wb * xb.y);
            ab.z = fmaf(ab.z, cb, wb * xb.z);
            ab.w = fmaf(ab.w, cb, wb * xb.w);
            mb = mnb;

            xa = na; xb = nb;
            s_nxt = s_n2;
        }
    }

    // merge the 4 group states: butterfly with exp rescale
#pragma unroll
    for (int off = 16; off <= 32; off <<= 1) {
        float mo = __shfl_xor(ma, off);
        float so = __shfl_xor(sa, off);
        float4 ao;
        ao.x = __shfl_xor(aa.x, off); ao.y = __shfl_xor(aa.y, off);
        ao.z = __shfl_xor(aa.z, off); ao.w = __shfl_xor(aa.w, off);
        float mn = fmaxf(ma, mo);
        float c0 = __expf(ma - mn), c1 = __expf(mo - mn);
        sa = fmaf(sa, c0, so * c1);
        aa.x = fmaf(aa.x, c0, ao.x * c1);
        aa.y = fmaf(aa.y, c0, ao.y * c1);
        aa.z = fmaf(aa.z, c0, ao.z * c1);
        aa.w = fmaf(aa.w, c0, ao.w * c1);
        ma = mn;

        mo = __shfl_xor(mb, off);
        so = __shfl_xor(sb, off);
        ao.x = __shfl_xor(ab.x, off); ao.y = __shfl_xor(ab.y, off);
        ao.z = __shfl_xor(ab.z, off); ao.w = __shfl_xor(ab.w, off);
        mn = fmaxf(mb, mo);
        c0 = __expf(mb - mn); c1 = __expf(mo - mn);
        sb = fmaf(sb, c0, so * c1);
        ab.x = fmaf(ab.x, c0, ao.x * c1);
        ab.y = fmaf(ab.y, c0, ao.y * c1);
        ab.z = fmaf(ab.z, c0, ao.z * c1);
        ab.w = fmaf(ab.w, c0, ao.w * c1);
        mb = mn;
    }

    float inva = 1.0f / (sa + 1e-16f);    // deg==0 -> acc=0 -> r=0
    float invb = 1.0f / (sb + 1e-16f);

    if (!FINAL) {
        if (lane < 16) {
            const float4 bv = *(const float4*)&bias[fo];
            float4 o;
            o.x = fmaf(0.5f, fmaf(aa.x, inva, ab.x * invb), bv.x);
            o.y = fmaf(0.5f, fmaf(aa.y, inva, ab.y * invb), bv.y);
            o.z = fmaf(0.5f, fmaf(aa.z, inva, ab.z * invb), bv.z);
            o.w = fmaf(0.5f, fmaf(aa.w, inva, ab.w * invb), bv.w);
            o.x = o.x > 0.f ? o.x : 0.01f * o.x;
            o.y = o.y > 0.f ? o.y : 0.01f * o.y;
            o.z = o.z > 0.f ? o.z : 0.01f * o.z;
            o.w = o.w > 0.f ? o.w : 0.01f * o.w;
            *(float4*)&xout[(size_t)node * DD + fo] = o;
        }
    } else {
        // epilogue GEMM: out = leaky(o @ Wo + bo, 0.01), o bounced through LDS
        __shared__ float sh_o[4][DD];
        if (lane < 16) {
            const float4 bv = *(const float4*)&bias[fo];
            float4 o;
            o.x = fmaf(0.5f, fmaf(aa.x, inva, ab.x * invb), bv.x);
            o.y = fmaf(0.5f, fmaf(aa.y, inva, ab.y * invb), bv.y);
            o.z = fmaf(0.5f, fmaf(aa.z, inva, ab.z * invb), bv.z);
            o.w = fmaf(0.5f, fmaf(aa.w, inva, ab.w * invb), bv.w);
            o.x = o.x > 0.f ? o.x : 0.01f * o.x;
            o.y = o.y > 0.f ? o.y : 0.01f * o.y;
            o.z = o.z > 0.f ? o.z : 0.01f * o.z;
            o.w = o.w > 0.f ? o.w : 0.01f * o.w;
            *(float4*)&sh_o[w][fo] = o;
        }
        __syncthreads();
        int j = lane;                      // output column
        float acc = bo[j];
#pragma unroll 4
        for (int k = 0; k < DD; ++k) {
            acc = fmaf(sh_o[w][k], Wo[k * DD + j], acc);
        }
        acc = acc > 0.f ? acc : 0.01f * acc;
        xout[(size_t)node * DD + j] = acc;
    }
}

extern "C" void kernel_launch(void* const* d_in, const int* in_sizes, int n_in,
                              void* d_out, int out_size, void* d_ws, size_t ws_size,
                              hipStream_t stream) {
    const int* edge_index = (const int*)d_in[0];
    const int* src = edge_index;
    const int* dst = edge_index + EE;
    // d_in[1] = edge_weight, unused
    const float* pert = (const float*)d_in[2];
    const float* Wl = (const float*)d_in[3];
    const float* bl = (const float*)d_in[4];
    const float* Wr = (const float*)d_in[5];
    const float* br = (const float*)d_in[6];
    const float* att = (const float*)d_in[7];
    const float* bias = (const float*)d_in[8];
    const float* Wo = (const float*)d_in[9];
    const float* bo = (const float*)d_in[10];
    float* out = (float*)d_out;

    // workspace carve-up
    char* w = (char*)d_ws;
    float* xl = (float*)w;            w += (size_t)NN * HD * 4;
    float* xr = (float*)w;            w += (size_t)NN * HD * 4;
    float* xb0 = (float*)w;           w += (size_t)NN * DD * 4;
    float* xb1 = (float*)w;           w += (size_t)NN * DD * 4;
    int* bdeg = (int*)w;              w += (size_t)NN * NB * 4;
    int* deg = (int*)w;               w += (size_t)NN * 4;
    int* offsets = (int*)w;           w += (size_t)(NN + 1) * 4 + 4; // keep alignment
    int* cursor = (int*)w;            w += (size_t)NN * NB * 4;
    int* csr_src = (int*)w;           w += (size_t)EE * 4;

    // Bucketed CSR build (dst is layer-invariant; built once per launch)
    hipMemsetAsync(bdeg, 0, (size_t)NN * NB * 4, stream);
    hist_kernel<<<(EE + 255) / 256, 256, 0, stream>>>(src, dst, bdeg);
    bucket_sum_kernel<<<(NN + 255) / 256, 256, 0, stream>>>(bdeg, deg);
    scan_kernel<<<1, 1024, 0, stream>>>(deg, offsets, NN);
    bucket_prefix_kernel<<<(NN + 255) / 256, 256, 0, stream>>>(bdeg, offsets, cursor);
    scatter_kernel<<<(EE + 255) / 256, 256, 0, stream>>>(src, dst, cursor, csr_src);

    const float* xin = pert;
    float* bufs[2] = {xb0, xb1};
    for (int l = 0; l < LL; ++l) {
        gemm_lr<<<NN / GR, 256, 0, stream>>>(xin, Wl + (size_t)l * DD * HD, bl + (size_t)l * HD,
                                             Wr + (size_t)l * DD * HD, br + (size_t)l * HD, xl, xr);
        if (l < LL - 1) {
            fused_aggregate<false><<<NN / 4, 256, 0, stream>>>(
                xl, xr, att + (size_t)l * HD, offsets, csr_src,
                bias + (size_t)l * DD, nullptr, nullptr, bufs[l & 1]);
            xin = bufs[l & 1];
        } else {
            fused_aggregate<true><<<NN / 4, 256, 0, stream>>>(
                xl, xr, att + (size_t)l * HD, offsets, csr_src,
                bias + (size_t)l * DD, Wo, bo, out);
        }
    }
}